// Round 5
// baseline (725.883 us; speedup 1.0000x reference)
//
#include <hip/hip_runtime.h>

// GCN: N=100000, E=1600000, F=H=128, D=64, O=1. fp32.
// R5: agg gather = quarter-wave float8 streams, unroll 2 (16 float4 in
//     flight/wave). CSR scatter packs (d&127)<<17|src into int32. Scan
//     kernels merged. GEMM unchanged (register-tiled 8x8).

#define F_DIM 128
#define CHUNK 8192

// ---- bucket histogram: hist[bin*NB + blk] = #edges of chunk blk in bucket bin
__global__ __launch_bounds__(256) void histH(const int* __restrict__ dst, int* __restrict__ hist,
                                             int E, int NBKT, int NB) {
    __shared__ int bins[1024];
    int blk = blockIdx.x;
    for (int i = threadIdx.x; i < NBKT; i += 256) bins[i] = 0;
    __syncthreads();
    int beg = blk * CHUNK, end = min(E, beg + CHUNK);
    for (int e = beg + threadIdx.x; e < end; e += 256)
        atomicAdd(&bins[dst[e] >> 7], 1);
    __syncthreads();
    for (int i = threadIdx.x; i < NBKT; i += 256)
        hist[i * NB + blk] = bins[i];
}

// ---- merged scan: bin totals -> binbase, hist -> running offsets (1 block)
__global__ __launch_bounds__(1024) void scan_all(int* __restrict__ hist,
                                                 int* __restrict__ binbase,
                                                 int NBKT, int NB, int E) {
    __shared__ int s[1024];
    int t = threadIdx.x;
    int v = 0;
    if (t < NBKT) {
        int sum = 0;
        for (int b = 0; b < NB; ++b) sum += hist[t * NB + b];
        v = sum;
    }
    s[t] = v;
    __syncthreads();
    for (int off = 1; off < 1024; off <<= 1) {
        int u = (t >= off) ? s[t - off] : 0;
        __syncthreads();
        s[t] += u;
        __syncthreads();
    }
    if (t < NBKT) binbase[t] = s[t] - v;
    if (t == 0) binbase[NBKT] = E;
    if (t < NBKT) {
        int run = s[t] - v;
        for (int b = 0; b < NB; ++b) {
            int c = hist[t * NB + b];
            hist[t * NB + b] = run;
            run += c;
        }
    }
}

// ---- bucketed scatter: tmp[] = (d&127)<<17 | src, grouped by bucket ----
__global__ __launch_bounds__(256) void scatterH(const int* __restrict__ src,
                                                const int* __restrict__ dst,
                                                const int* __restrict__ hist,
                                                int* __restrict__ tmp,
                                                int E, int NBKT, int NB) {
    __shared__ int offs[1024];
    int blk = blockIdx.x;
    for (int i = threadIdx.x; i < NBKT; i += 256) offs[i] = hist[i * NB + blk];
    __syncthreads();
    int beg = blk * CHUNK, end = min(E, beg + CHUNK);
    for (int e = beg + threadIdx.x; e < end; e += 256) {
        int d = dst[e];
        int pos = atomicAdd(&offs[d >> 7], 1);
        tmp[pos] = ((d & 127) << 17) | src[e];
    }
}

// ---- per-bucket CSR compaction: rowptr + srcidx ----
__global__ __launch_bounds__(256) void bucket_csr(const int* __restrict__ tmp,
                                                  const int* __restrict__ binbase,
                                                  int* __restrict__ rowptr,
                                                  int* __restrict__ srcidx,
                                                  int n) {
    __shared__ int cnt[128], sc[128], cnt2[128];
    int b = blockIdx.x;
    int bstart = binbase[b], bend = binbase[b + 1];
    if (threadIdx.x < 128) cnt[threadIdx.x] = 0;
    __syncthreads();
    for (int e = bstart + threadIdx.x; e < bend; e += 256)
        atomicAdd(&cnt[tmp[e] >> 17], 1);
    __syncthreads();
    if (threadIdx.x < 128) sc[threadIdx.x] = cnt[threadIdx.x];
    __syncthreads();
    for (int off = 1; off < 128; off <<= 1) {
        int u = 0;
        if (threadIdx.x < 128 && threadIdx.x >= off) u = sc[threadIdx.x - off];
        __syncthreads();
        if (threadIdx.x < 128) sc[threadIdx.x] += u;
        __syncthreads();
    }
    if (threadIdx.x < 128) {
        int excl = sc[threadIdx.x] - cnt[threadIdx.x];
        cnt2[threadIdx.x] = excl;
        int id = b * 128 + threadIdx.x;
        if (id <= n) rowptr[id] = bstart + excl;
    }
    __syncthreads();
    for (int e = bstart + threadIdx.x; e < bend; e += 256) {
        int p = tmp[e];
        int pos = bstart + atomicAdd(&cnt2[p >> 17], 1);
        srcidx[pos] = p & 0x1FFFF;
    }
}

__global__ void dinv_k(const int* __restrict__ rowptr, float* __restrict__ dinv, int n) {
    int i = blockIdx.x * blockDim.x + threadIdx.x;
    if (i < n) dinv[i] = rsqrtf((float)(rowptr[i + 1] - rowptr[i]) + 1.0f);
}

// ---- w3 = W2 @ Wo  [128], c3 = b2.Wo + bo ----
__global__ void make_w3(const float* __restrict__ W2, const float* __restrict__ b2,
                        const float* __restrict__ Wo, const float* __restrict__ bo,
                        float* __restrict__ w3, float* __restrict__ c3) {
    int j = threadIdx.x;
    float s = 0.f;
    for (int d = 0; d < 64; ++d) s += W2[j * 64 + d] * Wo[d];
    w3[j] = s;
    if (j == 0) {
        float c = 0.f;
        for (int d = 0; d < 64; ++d) c += b2[d] * Wo[d];
        *c3 = c + bo[0];
    }
}

// ---- fp32 GEMM  C[n,128] = dinv[row] * (A[n,128] @ W[128,128]) ----
#define BK 32
#define LDP 132
__global__ __launch_bounds__(256, 4) void gemm_rt(const float* __restrict__ A,
                                                  const float* __restrict__ W,
                                                  const float* __restrict__ dinv,
                                                  float* __restrict__ C, int n) {
    __shared__ float As[BK][LDP];
    __shared__ float Ws[BK][LDP];
    const int tid = threadIdx.x;
    const int tx = tid & 15;
    const int ty = tid >> 4;
    const int row0 = blockIdx.x * 128;

    float acc[8][8];
#pragma unroll
    for (int i = 0; i < 8; ++i)
#pragma unroll
        for (int j = 0; j < 8; ++j) acc[i][j] = 0.f;

    for (int kc = 0; kc < 128; kc += BK) {
#pragma unroll
        for (int i = 0; i < 4; ++i) {
            int idx = tid + 256 * i;
            int r = idx >> 3, q = idx & 7;
            int row = row0 + r;
            float4 v = (row < n) ? *(const float4*)(A + (size_t)row * 128 + kc + q * 4)
                                 : make_float4(0.f, 0.f, 0.f, 0.f);
            As[q * 4 + 0][r] = v.x;
            As[q * 4 + 1][r] = v.y;
            As[q * 4 + 2][r] = v.z;
            As[q * 4 + 3][r] = v.w;
        }
#pragma unroll
        for (int i = 0; i < 4; ++i) {
            int idx = tid + 256 * i;
            int k = idx >> 5, q = idx & 31;
            float4 v = *(const float4*)(W + (size_t)(kc + k) * 128 + q * 4);
            *(float4*)(&Ws[k][q * 4]) = v;
        }
        __syncthreads();

#pragma unroll 8
        for (int k = 0; k < BK; ++k) {
            float a[8], w[8];
            *(float4*)&a[0] = *(const float4*)(&As[k][ty * 4]);
            *(float4*)&a[4] = *(const float4*)(&As[k][64 + ty * 4]);
            *(float4*)&w[0] = *(const float4*)(&Ws[k][tx * 4]);
            *(float4*)&w[4] = *(const float4*)(&Ws[k][64 + tx * 4]);
#pragma unroll
            for (int i = 0; i < 8; ++i)
#pragma unroll
                for (int j = 0; j < 8; ++j)
                    acc[i][j] = fmaf(a[i], w[j], acc[i][j]);
        }
        __syncthreads();
    }

#pragma unroll
    for (int i = 0; i < 8; ++i) {
        int row = row0 + ty * 4 + (i & 3) + ((i >= 4) ? 64 : 0);
        if (row < n) {
            float di = dinv[row];
            float4 o0, o1;
            o0.x = acc[i][0] * di; o0.y = acc[i][1] * di;
            o0.z = acc[i][2] * di; o0.w = acc[i][3] * di;
            o1.x = acc[i][4] * di; o1.y = acc[i][5] * di;
            o1.z = acc[i][6] * di; o1.w = acc[i][7] * di;
            *(float4*)(C + (size_t)row * 128 + tx * 4) = o0;
            *(float4*)(C + (size_t)row * 128 + 64 + tx * 4) = o1;
        }
    }
}

// ---- CSR gather: one wave/node, 4 quarter-wave float8 edge streams ----
// out[d] = relu( dinv[d]*(sum_{s in in(d)} G[s] + G[d]) + b )
__global__ __launch_bounds__(256) void agg_csr128(const int* __restrict__ rowptr,
                                                  const int* __restrict__ srcidx,
                                                  const float* __restrict__ dinv,
                                                  const float* __restrict__ G,
                                                  const float* __restrict__ b,
                                                  float* __restrict__ out,
                                                  int n, int do_relu) {
    int wid = (int)((blockIdx.x * (size_t)blockDim.x + threadIdx.x) >> 6);
    if (wid >= n) return;
    int lane = threadIdx.x & 63;
    int q = lane >> 4;        // quarter 0..3: independent edge stream
    int l = lane & 15;        // float8 slot within the 128-float row
    int beg = rowptr[wid], end = rowptr[wid + 1];
    const int co = l * 8;

    float4 aLo = make_float4(0.f, 0.f, 0.f, 0.f);
    float4 aHi = make_float4(0.f, 0.f, 0.f, 0.f);
    if (q == 0) {  // self-loop term
        const float* rs = G + (size_t)wid * 128 + co;
        aLo = *(const float4*)rs;
        aHi = *(const float4*)(rs + 4);
    }

    int e = beg + q;
    // unroll 2: edges e and e+4 (per quarter), 4 float4 loads in flight/lane
    for (; e + 4 < end; e += 8) {
        int s0 = srcidx[e], s1 = srcidx[e + 4];
        const float* r0 = G + (size_t)s0 * 128 + co;
        const float* r1 = G + (size_t)s1 * 128 + co;
        float4 v0 = *(const float4*)r0;
        float4 v1 = *(const float4*)(r0 + 4);
        float4 v2 = *(const float4*)r1;
        float4 v3 = *(const float4*)(r1 + 4);
        aLo.x += v0.x + v2.x; aLo.y += v0.y + v2.y;
        aLo.z += v0.z + v2.z; aLo.w += v0.w + v2.w;
        aHi.x += v1.x + v3.x; aHi.y += v1.y + v3.y;
        aHi.z += v1.z + v3.z; aHi.w += v1.w + v3.w;
    }
    for (; e < end; e += 4) {
        int s0 = srcidx[e];
        const float* r0 = G + (size_t)s0 * 128 + co;
        float4 v0 = *(const float4*)r0;
        float4 v1 = *(const float4*)(r0 + 4);
        aLo.x += v0.x; aLo.y += v0.y; aLo.z += v0.z; aLo.w += v0.w;
        aHi.x += v1.x; aHi.y += v1.y; aHi.z += v1.z; aHi.w += v1.w;
    }

    // reduce across quarters: xor 16 then 32
    aLo.x += __shfl_xor(aLo.x, 16, 64); aLo.y += __shfl_xor(aLo.y, 16, 64);
    aLo.z += __shfl_xor(aLo.z, 16, 64); aLo.w += __shfl_xor(aLo.w, 16, 64);
    aHi.x += __shfl_xor(aHi.x, 16, 64); aHi.y += __shfl_xor(aHi.y, 16, 64);
    aHi.z += __shfl_xor(aHi.z, 16, 64); aHi.w += __shfl_xor(aHi.w, 16, 64);
    aLo.x += __shfl_xor(aLo.x, 32, 64); aLo.y += __shfl_xor(aLo.y, 32, 64);
    aLo.z += __shfl_xor(aLo.z, 32, 64); aLo.w += __shfl_xor(aLo.w, 32, 64);
    aHi.x += __shfl_xor(aHi.x, 32, 64); aHi.y += __shfl_xor(aHi.y, 32, 64);
    aHi.z += __shfl_xor(aHi.z, 32, 64); aHi.w += __shfl_xor(aHi.w, 32, 64);

    if (lane < 16) {
        float di = dinv[wid];
        float4 b0 = *(const float4*)(b + co);
        float4 b1 = *(const float4*)(b + co + 4);
        float4 o0, o1;
        o0.x = di * aLo.x + b0.x; o0.y = di * aLo.y + b0.y;
        o0.z = di * aLo.z + b0.z; o0.w = di * aLo.w + b0.w;
        o1.x = di * aHi.x + b1.x; o1.y = di * aHi.y + b1.y;
        o1.z = di * aHi.z + b1.z; o1.w = di * aHi.w + b1.w;
        if (do_relu) {
            o0.x = fmaxf(o0.x, 0.f); o0.y = fmaxf(o0.y, 0.f);
            o0.z = fmaxf(o0.z, 0.f); o0.w = fmaxf(o0.w, 0.f);
            o1.x = fmaxf(o1.x, 0.f); o1.y = fmaxf(o1.y, 0.f);
            o1.z = fmaxf(o1.z, 0.f); o1.w = fmaxf(o1.w, 0.f);
        }
        float* orow = out + (size_t)wid * 128 + co;
        *(float4*)orow = o0;
        *(float4*)(orow + 4) = o1;
    }
}

// ---- ys[i] = dinv[i] * dot(H[i,:], w3), one wave per row ----
__global__ __launch_bounds__(256) void dotw3(const float* __restrict__ H,
                                             const float* __restrict__ w3,
                                             const float* __restrict__ dinv,
                                             float* __restrict__ ys, int n) {
    int wid = (int)((blockIdx.x * (size_t)blockDim.x + threadIdx.x) >> 6);
    int lane = threadIdx.x & 63;
    if (wid >= n) return;
    float2 h = *(const float2*)(H + (size_t)wid * 128 + lane * 2);
    float2 w = *(const float2*)(w3 + lane * 2);
    float v = h.x * w.x + h.y * w.y;
#pragma unroll
    for (int off = 32; off > 0; off >>= 1) v += __shfl_down(v, off, 64);
    if (lane == 0) ys[wid] = v * dinv[wid];
}

// ---- scalar CSR gather for fused layer3+proj ----
__global__ void agg_csr_scalar(const int* __restrict__ rowptr, const int* __restrict__ srcidx,
                               const float* __restrict__ dinv, const float* __restrict__ ys,
                               const float* __restrict__ c3, float* __restrict__ out, int n) {
    int i = blockIdx.x * blockDim.x + threadIdx.x;
    if (i >= n) return;
    int beg = rowptr[i], end = rowptr[i + 1];
    float acc = ys[i];
    int e = beg;
    for (; e + 3 < end; e += 4) {
        acc += ys[srcidx[e]] + ys[srcidx[e + 1]] + ys[srcidx[e + 2]] + ys[srcidx[e + 3]];
    }
    for (; e < end; ++e) acc += ys[srcidx[e]];
    out[i] = dinv[i] * acc + c3[0];
}

static inline size_t align4(size_t x) { return (x + 3) & ~(size_t)3; }

extern "C" void kernel_launch(void* const* d_in, const int* in_sizes, int n_in,
                              void* d_out, int out_size, void* d_ws, size_t ws_size,
                              hipStream_t stream) {
    const float* x  = (const float*)d_in[0];
    const int* ei   = (const int*)d_in[1];
    const float* W1 = (const float*)d_in[2];
    const float* b1 = (const float*)d_in[3];
    const float* Wh = (const float*)d_in[4];
    const float* bh = (const float*)d_in[5];
    const float* W2 = (const float*)d_in[6];
    const float* b2 = (const float*)d_in[7];
    const float* Wo = (const float*)d_in[8];
    const float* bo = (const float*)d_in[9];
    float* out = (float*)d_out;

    const int n = in_sizes[0] / F_DIM;
    const int E = in_sizes[1] / 2;
    const int* src = ei;
    const int* dst = ei + E;

    const int NB = (E + CHUNK - 1) / CHUNK;
    const int NBKT = (n >> 7) + 1;

    size_t o = 0;
    int* rowptr = (int*)d_ws + o;        o = align4(o + n + 1);
    int* srcidx = (int*)d_ws + o;        o = align4(o + E);
    int* hist   = (int*)d_ws + o;        o = align4(o + (size_t)NBKT * NB);
    int* binbase= (int*)d_ws + o;        o = align4(o + NBKT + 1);
    float* dinv = (float*)d_ws + o;      o = align4(o + n);
    float* w3   = (float*)d_ws + o;      o = align4(o + 128);
    float* c3   = (float*)d_ws + o;      o = align4(o + 4);
    float* bufA = (float*)d_ws + o;      o = align4(o + (size_t)n * 128);
    float* bufB = (float*)d_ws + o;      o = align4(o + (size_t)n * 128);
    int* tmp = (int*)bufA;               // aliases bufA (consumed before gemm1)

    const int B = (n + 255) / 256;

    // CSR build
    histH<<<NB, 256, 0, stream>>>(dst, hist, E, NBKT, NB);
    scan_all<<<1, 1024, 0, stream>>>(hist, binbase, NBKT, NB, E);
    scatterH<<<NB, 256, 0, stream>>>(src, dst, hist, tmp, E, NBKT, NB);
    bucket_csr<<<NBKT, 256, 0, stream>>>(tmp, binbase, rowptr, srcidx, n);
    dinv_k<<<B, 256, 0, stream>>>(rowptr, dinv, n);
    make_w3<<<1, 128, 0, stream>>>(W2, b2, Wo, bo, w3, c3);

    const int GB = (n + 127) / 128;

    // layer 1
    gemm_rt<<<GB, 256, 0, stream>>>(x, W1, dinv, bufA, n);
    agg_csr128<<<(int)(((size_t)n * 64 + 255) / 256), 256, 0, stream>>>(
        rowptr, srcidx, dinv, bufA, b1, bufB, n, 1);

    // layer 2
    gemm_rt<<<GB, 256, 0, stream>>>(bufB, Wh, dinv, bufA, n);
    agg_csr128<<<(int)(((size_t)n * 64 + 255) / 256), 256, 0, stream>>>(
        rowptr, srcidx, dinv, bufA, bh, bufB, n, 1);

    // layer 3 + output projection
    dotw3<<<(int)(((size_t)n * 64 + 255) / 256), 256, 0, stream>>>(bufB, w3, dinv, bufA, n);
    agg_csr_scalar<<<B, 256, 0, stream>>>(rowptr, srcidx, dinv, bufA, c3, out, n);
}

// Round 6
// 516.093 us; speedup vs baseline: 1.4065x; 1.4065x over previous
//
#include <hip/hip_runtime.h>

// GCN: N=100000, E=1600000, F=H=128, D=64, O=1. fp32.
// R6: R5's agg (quarter-wave float8, unroll2) + R4's parallel 3-kernel scan
//     (R5's merged single-block scan_all was a 264us serialization bug).

#define F_DIM 128
#define CHUNK 8192

// ---- bucket histogram: hist[bin*NB + blk] = #edges of chunk blk in bucket bin
__global__ __launch_bounds__(256) void histH(const int* __restrict__ dst, int* __restrict__ hist,
                                             int E, int NBKT, int NB) {
    __shared__ int bins[1024];
    int blk = blockIdx.x;
    for (int i = threadIdx.x; i < NBKT; i += 256) bins[i] = 0;
    __syncthreads();
    int beg = blk * CHUNK, end = min(E, beg + CHUNK);
    for (int e = beg + threadIdx.x; e < end; e += 256)
        atomicAdd(&bins[dst[e] >> 7], 1);
    __syncthreads();
    for (int i = threadIdx.x; i < NBKT; i += 256)
        hist[i * NB + blk] = bins[i];
}

// ---- per-bin totals (parallel over bins) ----
__global__ void scanK1(const int* __restrict__ hist, int* __restrict__ binsum,
                       int NBKT, int NB) {
    int bin = blockIdx.x * 256 + threadIdx.x;
    if (bin >= NBKT) return;
    int s = 0;
    for (int b = 0; b < NB; ++b) s += hist[bin * NB + b];
    binsum[bin] = s;
}

// ---- exclusive scan of bin totals -> bucket bases (NBKT <= 1024) ----
__global__ void scanK2(const int* __restrict__ binsum, int* __restrict__ binbase,
                       int NBKT, int E) {
    __shared__ int s[1024];
    int t = threadIdx.x;
    int v = (t < NBKT) ? binsum[t] : 0;
    s[t] = v;
    __syncthreads();
    for (int off = 1; off < 1024; off <<= 1) {
        int u = (t >= off) ? s[t - off] : 0;
        __syncthreads();
        s[t] += u;
        __syncthreads();
    }
    if (t < NBKT) binbase[t] = s[t] - v;
    if (t == 0) binbase[NBKT] = E;
}

// ---- hist[bin][blk] -> global scattered base offset (parallel over bins) ----
__global__ void scanK3(int* __restrict__ hist, const int* __restrict__ binbase,
                       int NBKT, int NB) {
    int bin = blockIdx.x * 256 + threadIdx.x;
    if (bin >= NBKT) return;
    int run = binbase[bin];
    for (int b = 0; b < NB; ++b) {
        int t = hist[bin * NB + b];
        hist[bin * NB + b] = run;
        run += t;
    }
}

// ---- bucketed scatter: tmp[] = (d&127)<<17 | src, grouped by bucket ----
__global__ __launch_bounds__(256) void scatterH(const int* __restrict__ src,
                                                const int* __restrict__ dst,
                                                const int* __restrict__ hist,
                                                int* __restrict__ tmp,
                                                int E, int NBKT, int NB) {
    __shared__ int offs[1024];
    int blk = blockIdx.x;
    for (int i = threadIdx.x; i < NBKT; i += 256) offs[i] = hist[i * NB + blk];
    __syncthreads();
    int beg = blk * CHUNK, end = min(E, beg + CHUNK);
    for (int e = beg + threadIdx.x; e < end; e += 256) {
        int d = dst[e];
        int pos = atomicAdd(&offs[d >> 7], 1);
        tmp[pos] = ((d & 127) << 17) | src[e];
    }
}

// ---- per-bucket CSR compaction: rowptr + srcidx ----
__global__ __launch_bounds__(256) void bucket_csr(const int* __restrict__ tmp,
                                                  const int* __restrict__ binbase,
                                                  int* __restrict__ rowptr,
                                                  int* __restrict__ srcidx,
                                                  int n) {
    __shared__ int cnt[128], sc[128], cnt2[128];
    int b = blockIdx.x;
    int bstart = binbase[b], bend = binbase[b + 1];
    if (threadIdx.x < 128) cnt[threadIdx.x] = 0;
    __syncthreads();
    for (int e = bstart + threadIdx.x; e < bend; e += 256)
        atomicAdd(&cnt[tmp[e] >> 17], 1);
    __syncthreads();
    if (threadIdx.x < 128) sc[threadIdx.x] = cnt[threadIdx.x];
    __syncthreads();
    for (int off = 1; off < 128; off <<= 1) {
        int u = 0;
        if (threadIdx.x < 128 && threadIdx.x >= off) u = sc[threadIdx.x - off];
        __syncthreads();
        if (threadIdx.x < 128) sc[threadIdx.x] += u;
        __syncthreads();
    }
    if (threadIdx.x < 128) {
        int excl = sc[threadIdx.x] - cnt[threadIdx.x];
        cnt2[threadIdx.x] = excl;
        int id = b * 128 + threadIdx.x;
        if (id <= n) rowptr[id] = bstart + excl;
    }
    __syncthreads();
    for (int e = bstart + threadIdx.x; e < bend; e += 256) {
        int p = tmp[e];
        int pos = bstart + atomicAdd(&cnt2[p >> 17], 1);
        srcidx[pos] = p & 0x1FFFF;
    }
}

__global__ void dinv_k(const int* __restrict__ rowptr, float* __restrict__ dinv, int n) {
    int i = blockIdx.x * blockDim.x + threadIdx.x;
    if (i < n) dinv[i] = rsqrtf((float)(rowptr[i + 1] - rowptr[i]) + 1.0f);
}

// ---- w3 = W2 @ Wo  [128], c3 = b2.Wo + bo ----
__global__ void make_w3(const float* __restrict__ W2, const float* __restrict__ b2,
                        const float* __restrict__ Wo, const float* __restrict__ bo,
                        float* __restrict__ w3, float* __restrict__ c3) {
    int j = threadIdx.x;
    float s = 0.f;
    for (int d = 0; d < 64; ++d) s += W2[j * 64 + d] * Wo[d];
    w3[j] = s;
    if (j == 0) {
        float c = 0.f;
        for (int d = 0; d < 64; ++d) c += b2[d] * Wo[d];
        *c3 = c + bo[0];
    }
}

// ---- fp32 GEMM  C[n,128] = dinv[row] * (A[n,128] @ W[128,128]) ----
#define BK 32
#define LDP 132
__global__ __launch_bounds__(256, 4) void gemm_rt(const float* __restrict__ A,
                                                  const float* __restrict__ W,
                                                  const float* __restrict__ dinv,
                                                  float* __restrict__ C, int n) {
    __shared__ float As[BK][LDP];
    __shared__ float Ws[BK][LDP];
    const int tid = threadIdx.x;
    const int tx = tid & 15;
    const int ty = tid >> 4;
    const int row0 = blockIdx.x * 128;

    float acc[8][8];
#pragma unroll
    for (int i = 0; i < 8; ++i)
#pragma unroll
        for (int j = 0; j < 8; ++j) acc[i][j] = 0.f;

    for (int kc = 0; kc < 128; kc += BK) {
#pragma unroll
        for (int i = 0; i < 4; ++i) {
            int idx = tid + 256 * i;
            int r = idx >> 3, q = idx & 7;
            int row = row0 + r;
            float4 v = (row < n) ? *(const float4*)(A + (size_t)row * 128 + kc + q * 4)
                                 : make_float4(0.f, 0.f, 0.f, 0.f);
            As[q * 4 + 0][r] = v.x;
            As[q * 4 + 1][r] = v.y;
            As[q * 4 + 2][r] = v.z;
            As[q * 4 + 3][r] = v.w;
        }
#pragma unroll
        for (int i = 0; i < 4; ++i) {
            int idx = tid + 256 * i;
            int k = idx >> 5, q = idx & 31;
            float4 v = *(const float4*)(W + (size_t)(kc + k) * 128 + q * 4);
            *(float4*)(&Ws[k][q * 4]) = v;
        }
        __syncthreads();

#pragma unroll 8
        for (int k = 0; k < BK; ++k) {
            float a[8], w[8];
            *(float4*)&a[0] = *(const float4*)(&As[k][ty * 4]);
            *(float4*)&a[4] = *(const float4*)(&As[k][64 + ty * 4]);
            *(float4*)&w[0] = *(const float4*)(&Ws[k][tx * 4]);
            *(float4*)&w[4] = *(const float4*)(&Ws[k][64 + tx * 4]);
#pragma unroll
            for (int i = 0; i < 8; ++i)
#pragma unroll
                for (int j = 0; j < 8; ++j)
                    acc[i][j] = fmaf(a[i], w[j], acc[i][j]);
        }
        __syncthreads();
    }

#pragma unroll
    for (int i = 0; i < 8; ++i) {
        int row = row0 + ty * 4 + (i & 3) + ((i >= 4) ? 64 : 0);
        if (row < n) {
            float di = dinv[row];
            float4 o0, o1;
            o0.x = acc[i][0] * di; o0.y = acc[i][1] * di;
            o0.z = acc[i][2] * di; o0.w = acc[i][3] * di;
            o1.x = acc[i][4] * di; o1.y = acc[i][5] * di;
            o1.z = acc[i][6] * di; o1.w = acc[i][7] * di;
            *(float4*)(C + (size_t)row * 128 + tx * 4) = o0;
            *(float4*)(C + (size_t)row * 128 + 64 + tx * 4) = o1;
        }
    }
}

// ---- CSR gather: one wave/node, 4 quarter-wave float8 edge streams ----
__global__ __launch_bounds__(256) void agg_csr128(const int* __restrict__ rowptr,
                                                  const int* __restrict__ srcidx,
                                                  const float* __restrict__ dinv,
                                                  const float* __restrict__ G,
                                                  const float* __restrict__ b,
                                                  float* __restrict__ out,
                                                  int n, int do_relu) {
    int wid = (int)((blockIdx.x * (size_t)blockDim.x + threadIdx.x) >> 6);
    if (wid >= n) return;
    int lane = threadIdx.x & 63;
    int q = lane >> 4;        // quarter 0..3: independent edge stream
    int l = lane & 15;        // float8 slot within the 128-float row
    int beg = rowptr[wid], end = rowptr[wid + 1];
    const int co = l * 8;

    float4 aLo = make_float4(0.f, 0.f, 0.f, 0.f);
    float4 aHi = make_float4(0.f, 0.f, 0.f, 0.f);
    if (q == 0) {  // self-loop term
        const float* rs = G + (size_t)wid * 128 + co;
        aLo = *(const float4*)rs;
        aHi = *(const float4*)(rs + 4);
    }

    int e = beg + q;
    for (; e + 4 < end; e += 8) {
        int s0 = srcidx[e], s1 = srcidx[e + 4];
        const float* r0 = G + (size_t)s0 * 128 + co;
        const float* r1 = G + (size_t)s1 * 128 + co;
        float4 v0 = *(const float4*)r0;
        float4 v1 = *(const float4*)(r0 + 4);
        float4 v2 = *(const float4*)r1;
        float4 v3 = *(const float4*)(r1 + 4);
        aLo.x += v0.x + v2.x; aLo.y += v0.y + v2.y;
        aLo.z += v0.z + v2.z; aLo.w += v0.w + v2.w;
        aHi.x += v1.x + v3.x; aHi.y += v1.y + v3.y;
        aHi.z += v1.z + v3.z; aHi.w += v1.w + v3.w;
    }
    for (; e < end; e += 4) {
        int s0 = srcidx[e];
        const float* r0 = G + (size_t)s0 * 128 + co;
        float4 v0 = *(const float4*)r0;
        float4 v1 = *(const float4*)(r0 + 4);
        aLo.x += v0.x; aLo.y += v0.y; aLo.z += v0.z; aLo.w += v0.w;
        aHi.x += v1.x; aHi.y += v1.y; aHi.z += v1.z; aHi.w += v1.w;
    }

    aLo.x += __shfl_xor(aLo.x, 16, 64); aLo.y += __shfl_xor(aLo.y, 16, 64);
    aLo.z += __shfl_xor(aLo.z, 16, 64); aLo.w += __shfl_xor(aLo.w, 16, 64);
    aHi.x += __shfl_xor(aHi.x, 16, 64); aHi.y += __shfl_xor(aHi.y, 16, 64);
    aHi.z += __shfl_xor(aHi.z, 16, 64); aHi.w += __shfl_xor(aHi.w, 16, 64);
    aLo.x += __shfl_xor(aLo.x, 32, 64); aLo.y += __shfl_xor(aLo.y, 32, 64);
    aLo.z += __shfl_xor(aLo.z, 32, 64); aLo.w += __shfl_xor(aLo.w, 32, 64);
    aHi.x += __shfl_xor(aHi.x, 32, 64); aHi.y += __shfl_xor(aHi.y, 32, 64);
    aHi.z += __shfl_xor(aHi.z, 32, 64); aHi.w += __shfl_xor(aHi.w, 32, 64);

    if (lane < 16) {
        float di = dinv[wid];
        float4 b0 = *(const float4*)(b + co);
        float4 b1 = *(const float4*)(b + co + 4);
        float4 o0, o1;
        o0.x = di * aLo.x + b0.x; o0.y = di * aLo.y + b0.y;
        o0.z = di * aLo.z + b0.z; o0.w = di * aLo.w + b0.w;
        o1.x = di * aHi.x + b1.x; o1.y = di * aHi.y + b1.y;
        o1.z = di * aHi.z + b1.z; o1.w = di * aHi.w + b1.w;
        if (do_relu) {
            o0.x = fmaxf(o0.x, 0.f); o0.y = fmaxf(o0.y, 0.f);
            o0.z = fmaxf(o0.z, 0.f); o0.w = fmaxf(o0.w, 0.f);
            o1.x = fmaxf(o1.x, 0.f); o1.y = fmaxf(o1.y, 0.f);
            o1.z = fmaxf(o1.z, 0.f); o1.w = fmaxf(o1.w, 0.f);
        }
        float* orow = out + (size_t)wid * 128 + co;
        *(float4*)orow = o0;
        *(float4*)(orow + 4) = o1;
    }
}

// ---- ys[i] = dinv[i] * dot(H[i,:], w3), one wave per row ----
__global__ __launch_bounds__(256) void dotw3(const float* __restrict__ H,
                                             const float* __restrict__ w3,
                                             const float* __restrict__ dinv,
                                             float* __restrict__ ys, int n) {
    int wid = (int)((blockIdx.x * (size_t)blockDim.x + threadIdx.x) >> 6);
    int lane = threadIdx.x & 63;
    if (wid >= n) return;
    float2 h = *(const float2*)(H + (size_t)wid * 128 + lane * 2);
    float2 w = *(const float2*)(w3 + lane * 2);
    float v = h.x * w.x + h.y * w.y;
#pragma unroll
    for (int off = 32; off > 0; off >>= 1) v += __shfl_down(v, off, 64);
    if (lane == 0) ys[wid] = v * dinv[wid];
}

// ---- scalar CSR gather for fused layer3+proj ----
__global__ void agg_csr_scalar(const int* __restrict__ rowptr, const int* __restrict__ srcidx,
                               const float* __restrict__ dinv, const float* __restrict__ ys,
                               const float* __restrict__ c3, float* __restrict__ out, int n) {
    int i = blockIdx.x * blockDim.x + threadIdx.x;
    if (i >= n) return;
    int beg = rowptr[i], end = rowptr[i + 1];
    float acc = ys[i];
    int e = beg;
    for (; e + 3 < end; e += 4) {
        acc += ys[srcidx[e]] + ys[srcidx[e + 1]] + ys[srcidx[e + 2]] + ys[srcidx[e + 3]];
    }
    for (; e < end; ++e) acc += ys[srcidx[e]];
    out[i] = dinv[i] * acc + c3[0];
}

static inline size_t align4(size_t x) { return (x + 3) & ~(size_t)3; }

extern "C" void kernel_launch(void* const* d_in, const int* in_sizes, int n_in,
                              void* d_out, int out_size, void* d_ws, size_t ws_size,
                              hipStream_t stream) {
    const float* x  = (const float*)d_in[0];
    const int* ei   = (const int*)d_in[1];
    const float* W1 = (const float*)d_in[2];
    const float* b1 = (const float*)d_in[3];
    const float* Wh = (const float*)d_in[4];
    const float* bh = (const float*)d_in[5];
    const float* W2 = (const float*)d_in[6];
    const float* b2 = (const float*)d_in[7];
    const float* Wo = (const float*)d_in[8];
    const float* bo = (const float*)d_in[9];
    float* out = (float*)d_out;

    const int n = in_sizes[0] / F_DIM;
    const int E = in_sizes[1] / 2;
    const int* src = ei;
    const int* dst = ei + E;

    const int NB = (E + CHUNK - 1) / CHUNK;
    const int NBKT = (n >> 7) + 1;

    size_t o = 0;
    int* rowptr = (int*)d_ws + o;        o = align4(o + n + 1);
    int* srcidx = (int*)d_ws + o;        o = align4(o + E);
    int* hist   = (int*)d_ws + o;        o = align4(o + (size_t)NBKT * NB);
    int* binsum = (int*)d_ws + o;        o = align4(o + NBKT);
    int* binbase= (int*)d_ws + o;        o = align4(o + NBKT + 1);
    float* dinv = (float*)d_ws + o;      o = align4(o + n);
    float* w3   = (float*)d_ws + o;      o = align4(o + 128);
    float* c3   = (float*)d_ws + o;      o = align4(o + 4);
    float* bufA = (float*)d_ws + o;      o = align4(o + (size_t)n * 128);
    float* bufB = (float*)d_ws + o;      o = align4(o + (size_t)n * 128);
    int* tmp = (int*)bufA;               // aliases bufA (consumed before gemm1)

    const int B = (n + 255) / 256;

    // CSR build
    histH<<<NB, 256, 0, stream>>>(dst, hist, E, NBKT, NB);
    scanK1<<<(NBKT + 255) / 256, 256, 0, stream>>>(hist, binsum, NBKT, NB);
    scanK2<<<1, 1024, 0, stream>>>(binsum, binbase, NBKT, E);
    scanK3<<<(NBKT + 255) / 256, 256, 0, stream>>>(hist, binbase, NBKT, NB);
    scatterH<<<NB, 256, 0, stream>>>(src, dst, hist, tmp, E, NBKT, NB);
    bucket_csr<<<NBKT, 256, 0, stream>>>(tmp, binbase, rowptr, srcidx, n);
    dinv_k<<<B, 256, 0, stream>>>(rowptr, dinv, n);
    make_w3<<<1, 128, 0, stream>>>(W2, b2, Wo, bo, w3, c3);

    const int GB = (n + 127) / 128;

    // layer 1
    gemm_rt<<<GB, 256, 0, stream>>>(x, W1, dinv, bufA, n);
    agg_csr128<<<(int)(((size_t)n * 64 + 255) / 256), 256, 0, stream>>>(
        rowptr, srcidx, dinv, bufA, b1, bufB, n, 1);

    // layer 2
    gemm_rt<<<GB, 256, 0, stream>>>(bufB, Wh, dinv, bufA, n);
    agg_csr128<<<(int)(((size_t)n * 64 + 255) / 256), 256, 0, stream>>>(
        rowptr, srcidx, dinv, bufA, bh, bufB, n, 1);

    // layer 3 + output projection
    dotw3<<<(int)(((size_t)n * 64 + 255) / 256), 256, 0, stream>>>(bufB, w3, dinv, bufA, n);
    agg_csr_scalar<<<B, 256, 0, stream>>>(rowptr, srcidx, dinv, bufA, c3, out, n);
}

// Round 7
// 412.654 us; speedup vs baseline: 1.7591x; 1.2507x over previous
//
#include <hip/hip_runtime.h>
#include <hip/hip_fp16.h>

// GCN: N=100000, E=1600000, F=H=128, D=64, O=1.
// R7: fp16 gather table. GEMM writes g = dinv*(A@W) as fp16 (256B rows);
//     agg gathers fp16, accumulates fp32, outputs fp32. Halves the
//     structural 8x51MB per-XCD L2-miss traffic of the random gather.
//     dinv folded into bucket_csr. ys reuses the fp16 buffer (free by then).

#define F_DIM 128
#define CHUNK 8192

__global__ __launch_bounds__(256) void histH(const int* __restrict__ dst, int* __restrict__ hist,
                                             int E, int NBKT, int NB) {
    __shared__ int bins[1024];
    int blk = blockIdx.x;
    for (int i = threadIdx.x; i < NBKT; i += 256) bins[i] = 0;
    __syncthreads();
    int beg = blk * CHUNK, end = min(E, beg + CHUNK);
    for (int e = beg + threadIdx.x; e < end; e += 256)
        atomicAdd(&bins[dst[e] >> 7], 1);
    __syncthreads();
    for (int i = threadIdx.x; i < NBKT; i += 256)
        hist[i * NB + blk] = bins[i];
}

__global__ void scanK1(const int* __restrict__ hist, int* __restrict__ binsum,
                       int NBKT, int NB) {
    int bin = blockIdx.x * 256 + threadIdx.x;
    if (bin >= NBKT) return;
    int s = 0;
    for (int b = 0; b < NB; ++b) s += hist[bin * NB + b];
    binsum[bin] = s;
}

__global__ void scanK2(const int* __restrict__ binsum, int* __restrict__ binbase,
                       int NBKT, int E) {
    __shared__ int s[1024];
    int t = threadIdx.x;
    int v = (t < NBKT) ? binsum[t] : 0;
    s[t] = v;
    __syncthreads();
    for (int off = 1; off < 1024; off <<= 1) {
        int u = (t >= off) ? s[t - off] : 0;
        __syncthreads();
        s[t] += u;
        __syncthreads();
    }
    if (t < NBKT) binbase[t] = s[t] - v;
    if (t == 0) binbase[NBKT] = E;
}

__global__ void scanK3(int* __restrict__ hist, const int* __restrict__ binbase,
                       int NBKT, int NB) {
    int bin = blockIdx.x * 256 + threadIdx.x;
    if (bin >= NBKT) return;
    int run = binbase[bin];
    for (int b = 0; b < NB; ++b) {
        int t = hist[bin * NB + b];
        hist[bin * NB + b] = run;
        run += t;
    }
}

__global__ __launch_bounds__(256) void scatterH(const int* __restrict__ src,
                                                const int* __restrict__ dst,
                                                const int* __restrict__ hist,
                                                int* __restrict__ tmp,
                                                int E, int NBKT, int NB) {
    __shared__ int offs[1024];
    int blk = blockIdx.x;
    for (int i = threadIdx.x; i < NBKT; i += 256) offs[i] = hist[i * NB + blk];
    __syncthreads();
    int beg = blk * CHUNK, end = min(E, beg + CHUNK);
    for (int e = beg + threadIdx.x; e < end; e += 256) {
        int d = dst[e];
        int pos = atomicAdd(&offs[d >> 7], 1);
        tmp[pos] = ((d & 127) << 17) | src[e];
    }
}

__global__ __launch_bounds__(256) void bucket_csr(const int* __restrict__ tmp,
                                                  const int* __restrict__ binbase,
                                                  int* __restrict__ rowptr,
                                                  int* __restrict__ srcidx,
                                                  float* __restrict__ dinv,
                                                  int n) {
    __shared__ int cnt[128], sc[128], cnt2[128];
    int b = blockIdx.x;
    int bstart = binbase[b], bend = binbase[b + 1];
    if (threadIdx.x < 128) cnt[threadIdx.x] = 0;
    __syncthreads();
    for (int e = bstart + threadIdx.x; e < bend; e += 256)
        atomicAdd(&cnt[tmp[e] >> 17], 1);
    __syncthreads();
    if (threadIdx.x < 128) sc[threadIdx.x] = cnt[threadIdx.x];
    __syncthreads();
    for (int off = 1; off < 128; off <<= 1) {
        int u = 0;
        if (threadIdx.x < 128 && threadIdx.x >= off) u = sc[threadIdx.x - off];
        __syncthreads();
        if (threadIdx.x < 128) sc[threadIdx.x] += u;
        __syncthreads();
    }
    if (threadIdx.x < 128) {
        int excl = sc[threadIdx.x] - cnt[threadIdx.x];
        cnt2[threadIdx.x] = excl;
        int id = b * 128 + threadIdx.x;
        if (id <= n) rowptr[id] = bstart + excl;
        if (id < n) dinv[id] = rsqrtf((float)cnt[threadIdx.x] + 1.0f);
    }
    __syncthreads();
    for (int e = bstart + threadIdx.x; e < bend; e += 256) {
        int p = tmp[e];
        int pos = bstart + atomicAdd(&cnt2[p >> 17], 1);
        srcidx[pos] = p & 0x1FFFF;
    }
}

__global__ void make_w3(const float* __restrict__ W2, const float* __restrict__ b2,
                        const float* __restrict__ Wo, const float* __restrict__ bo,
                        float* __restrict__ w3, float* __restrict__ c3) {
    int j = threadIdx.x;
    float s = 0.f;
    for (int d = 0; d < 64; ++d) s += W2[j * 64 + d] * Wo[d];
    w3[j] = s;
    if (j == 0) {
        float c = 0.f;
        for (int d = 0; d < 64; ++d) c += b2[d] * Wo[d];
        *c3 = c + bo[0];
    }
}

#define BK 32
#define LDP 132
__global__ __launch_bounds__(256, 4) void gemm_rt(const float* __restrict__ A,
                                                  const float* __restrict__ W,
                                                  const float* __restrict__ dinv,
                                                  __half* __restrict__ Ch, int n) {
    __shared__ float As[BK][LDP];
    __shared__ float Ws[BK][LDP];
    const int tid = threadIdx.x;
    const int tx = tid & 15;
    const int ty = tid >> 4;
    const int row0 = blockIdx.x * 128;

    float acc[8][8];
#pragma unroll
    for (int i = 0; i < 8; ++i)
#pragma unroll
        for (int j = 0; j < 8; ++j) acc[i][j] = 0.f;

    for (int kc = 0; kc < 128; kc += BK) {
#pragma unroll
        for (int i = 0; i < 4; ++i) {
            int idx = tid + 256 * i;
            int r = idx >> 3, q = idx & 7;
            int row = row0 + r;
            float4 v = (row < n) ? *(const float4*)(A + (size_t)row * 128 + kc + q * 4)
                                 : make_float4(0.f, 0.f, 0.f, 0.f);
            As[q * 4 + 0][r] = v.x;
            As[q * 4 + 1][r] = v.y;
            As[q * 4 + 2][r] = v.z;
            As[q * 4 + 3][r] = v.w;
        }
#pragma unroll
        for (int i = 0; i < 4; ++i) {
            int idx = tid + 256 * i;
            int k = idx >> 5, q = idx & 31;
            float4 v = *(const float4*)(W + (size_t)(kc + k) * 128 + q * 4);
            *(float4*)(&Ws[k][q * 4]) = v;
        }
        __syncthreads();

#pragma unroll 8
        for (int k = 0; k < BK; ++k) {
            float a[8], w[8];
            *(float4*)&a[0] = *(const float4*)(&As[k][ty * 4]);
            *(float4*)&a[4] = *(const float4*)(&As[k][64 + ty * 4]);
            *(float4*)&w[0] = *(const float4*)(&Ws[k][tx * 4]);
            *(float4*)&w[4] = *(const float4*)(&Ws[k][64 + tx * 4]);
#pragma unroll
            for (int i = 0; i < 8; ++i)
#pragma unroll
                for (int j = 0; j < 8; ++j)
                    acc[i][j] = fmaf(a[i], w[j], acc[i][j]);
        }
        __syncthreads();
    }

#pragma unroll
    for (int i = 0; i < 8; ++i) {
        int row = row0 + ty * 4 + (i & 3) + ((i >= 4) ? 64 : 0);
        if (row < n) {
            float di = dinv[row];
            __half2 p0 = __floats2half2_rn(acc[i][0] * di, acc[i][1] * di);
            __half2 p1 = __floats2half2_rn(acc[i][2] * di, acc[i][3] * di);
            __half2 p2 = __floats2half2_rn(acc[i][4] * di, acc[i][5] * di);
            __half2 p3 = __floats2half2_rn(acc[i][6] * di, acc[i][7] * di);
            uint2 w0, w1;
            w0.x = *(unsigned*)&p0; w0.y = *(unsigned*)&p1;
            w1.x = *(unsigned*)&p2; w1.y = *(unsigned*)&p3;
            *(uint2*)(Ch + (size_t)row * 128 + tx * 4) = w0;
            *(uint2*)(Ch + (size_t)row * 128 + 64 + tx * 4) = w1;
        }
    }
}

// out[d] = relu( dinv[d]*(sum_{s in in(d)} G[s] + G[d]) + b ), G fp16, accum fp32
__global__ __launch_bounds__(256) void agg_csr128(const int* __restrict__ rowptr,
                                                  const int* __restrict__ srcidx,
                                                  const float* __restrict__ dinv,
                                                  const __half* __restrict__ Gh,
                                                  const float* __restrict__ b,
                                                  float* __restrict__ out,
                                                  int n, int do_relu) {
    int wid = (int)((blockIdx.x * (size_t)blockDim.x + threadIdx.x) >> 6);
    if (wid >= n) return;
    int lane = threadIdx.x & 63;
    int q = lane >> 4;
    int l = lane & 15;
    int beg = rowptr[wid], end = rowptr[wid + 1];
    const int co = l * 8;

    float4 aLo = make_float4(0.f, 0.f, 0.f, 0.f);
    float4 aHi = make_float4(0.f, 0.f, 0.f, 0.f);

#define ACC16(u)                                                            \
    {                                                                       \
        float2 f0 = __half22float2(*(const __half2*)&(u).x);                \
        float2 f1 = __half22float2(*(const __half2*)&(u).y);                \
        float2 f2 = __half22float2(*(const __half2*)&(u).z);                \
        float2 f3 = __half22float2(*(const __half2*)&(u).w);                \
        aLo.x += f0.x; aLo.y += f0.y; aLo.z += f1.x; aLo.w += f1.y;         \
        aHi.x += f2.x; aHi.y += f2.y; aHi.z += f3.x; aHi.w += f3.y;         \
    }

    if (q == 0) {
        uint4 u = *(const uint4*)(Gh + (size_t)wid * 128 + co);
        ACC16(u);
    }

    int e = beg + q;
    for (; e + 4 < end; e += 8) {
        int s0 = srcidx[e], s1 = srcidx[e + 4];
        uint4 u0 = *(const uint4*)(Gh + (size_t)s0 * 128 + co);
        uint4 u1 = *(const uint4*)(Gh + (size_t)s1 * 128 + co);
        ACC16(u0);
        ACC16(u1);
    }
    for (; e < end; e += 4) {
        int s0 = srcidx[e];
        uint4 u0 = *(const uint4*)(Gh + (size_t)s0 * 128 + co);
        ACC16(u0);
    }
#undef ACC16

    aLo.x += __shfl_xor(aLo.x, 16, 64); aLo.y += __shfl_xor(aLo.y, 16, 64);
    aLo.z += __shfl_xor(aLo.z, 16, 64); aLo.w += __shfl_xor(aLo.w, 16, 64);
    aHi.x += __shfl_xor(aHi.x, 16, 64); aHi.y += __shfl_xor(aHi.y, 16, 64);
    aHi.z += __shfl_xor(aHi.z, 16, 64); aHi.w += __shfl_xor(aHi.w, 16, 64);
    aLo.x += __shfl_xor(aLo.x, 32, 64); aLo.y += __shfl_xor(aLo.y, 32, 64);
    aLo.z += __shfl_xor(aLo.z, 32, 64); aLo.w += __shfl_xor(aLo.w, 32, 64);
    aHi.x += __shfl_xor(aHi.x, 32, 64); aHi.y += __shfl_xor(aHi.y, 32, 64);
    aHi.z += __shfl_xor(aHi.z, 32, 64); aHi.w += __shfl_xor(aHi.w, 32, 64);

    if (lane < 16) {
        float di = dinv[wid];
        float4 b0 = *(const float4*)(b + co);
        float4 b1 = *(const float4*)(b + co + 4);
        float4 o0, o1;
        o0.x = di * aLo.x + b0.x; o0.y = di * aLo.y + b0.y;
        o0.z = di * aLo.z + b0.z; o0.w = di * aLo.w + b0.w;
        o1.x = di * aHi.x + b1.x; o1.y = di * aHi.y + b1.y;
        o1.z = di * aHi.z + b1.z; o1.w = di * aHi.w + b1.w;
        if (do_relu) {
            o0.x = fmaxf(o0.x, 0.f); o0.y = fmaxf(o0.y, 0.f);
            o0.z = fmaxf(o0.z, 0.f); o0.w = fmaxf(o0.w, 0.f);
            o1.x = fmaxf(o1.x, 0.f); o1.y = fmaxf(o1.y, 0.f);
            o1.z = fmaxf(o1.z, 0.f); o1.w = fmaxf(o1.w, 0.f);
        }
        float* orow = out + (size_t)wid * 128 + co;
        *(float4*)orow = o0;
        *(float4*)(orow + 4) = o1;
    }
}

__global__ __launch_bounds__(256) void dotw3(const float* __restrict__ H,
                                             const float* __restrict__ w3,
                                             const float* __restrict__ dinv,
                                             float* __restrict__ ys, int n) {
    int wid = (int)((blockIdx.x * (size_t)blockDim.x + threadIdx.x) >> 6);
    int lane = threadIdx.x & 63;
    if (wid >= n) return;
    float2 h = *(const float2*)(H + (size_t)wid * 128 + lane * 2);
    float2 w = *(const float2*)(w3 + lane * 2);
    float v = h.x * w.x + h.y * w.y;
#pragma unroll
    for (int off = 32; off > 0; off >>= 1) v += __shfl_down(v, off, 64);
    if (lane == 0) ys[wid] = v * dinv[wid];
}

__global__ void agg_csr_scalar(const int* __restrict__ rowptr, const int* __restrict__ srcidx,
                               const float* __restrict__ dinv, const float* __restrict__ ys,
                               const float* __restrict__ c3, float* __restrict__ out, int n) {
    int i = blockIdx.x * blockDim.x + threadIdx.x;
    if (i >= n) return;
    int beg = rowptr[i], end = rowptr[i + 1];
    float acc = ys[i];
    int e = beg;
    for (; e + 3 < end; e += 4) {
        acc += ys[srcidx[e]] + ys[srcidx[e + 1]] + ys[srcidx[e + 2]] + ys[srcidx[e + 3]];
    }
    for (; e < end; ++e) acc += ys[srcidx[e]];
    out[i] = dinv[i] * acc + c3[0];
}

static inline size_t align4(size_t x) { return (x + 3) & ~(size_t)3; }

extern "C" void kernel_launch(void* const* d_in, const int* in_sizes, int n_in,
                              void* d_out, int out_size, void* d_ws, size_t ws_size,
                              hipStream_t stream) {
    const float* x  = (const float*)d_in[0];
    const int* ei   = (const int*)d_in[1];
    const float* W1 = (const float*)d_in[2];
    const float* b1 = (const float*)d_in[3];
    const float* Wh = (const float*)d_in[4];
    const float* bh = (const float*)d_in[5];
    const float* W2 = (const float*)d_in[6];
    const float* b2 = (const float*)d_in[7];
    const float* Wo = (const float*)d_in[8];
    const float* bo = (const float*)d_in[9];
    float* out = (float*)d_out;

    const int n = in_sizes[0] / F_DIM;
    const int E = in_sizes[1] / 2;
    const int* src = ei;
    const int* dst = ei + E;

    const int NB = (E + CHUNK - 1) / CHUNK;
    const int NBKT = (n >> 7) + 1;

    size_t o = 0;
    int* rowptr = (int*)d_ws + o;        o = align4(o + n + 1);
    int* srcidx = (int*)d_ws + o;        o = align4(o + E);
    int* hist   = (int*)d_ws + o;        o = align4(o + (size_t)NBKT * NB);
    int* binsum = (int*)d_ws + o;        o = align4(o + NBKT);
    int* binbase= (int*)d_ws + o;        o = align4(o + NBKT + 1);
    float* dinv = (float*)d_ws + o;      o = align4(o + n);
    float* w3   = (float*)d_ws + o;      o = align4(o + 128);
    float* c3   = (float*)d_ws + o;      o = align4(o + 4);
    __half* bufA16 = (__half*)((int*)d_ws + o);  o = align4(o + (size_t)n * 64);  // n*128 halfs
    float* bufB = (float*)d_ws + o;      o = align4(o + (size_t)n * 128);
    int* tmp = (int*)bufA16;             // aliases bufA16 (consumed before gemm1)
    float* ys = (float*)bufA16;          // aliases bufA16 (free after agg2)

    const int B = (n + 255) / 256;

    // CSR build
    histH<<<NB, 256, 0, stream>>>(dst, hist, E, NBKT, NB);
    scanK1<<<(NBKT + 255) / 256, 256, 0, stream>>>(hist, binsum, NBKT, NB);
    scanK2<<<1, 1024, 0, stream>>>(binsum, binbase, NBKT, E);
    scanK3<<<(NBKT + 255) / 256, 256, 0, stream>>>(hist, binbase, NBKT, NB);
    scatterH<<<NB, 256, 0, stream>>>(src, dst, hist, tmp, E, NBKT, NB);
    bucket_csr<<<NBKT, 256, 0, stream>>>(tmp, binbase, rowptr, srcidx, dinv, n);
    make_w3<<<1, 128, 0, stream>>>(W2, b2, Wo, bo, w3, c3);

    const int GB = (n + 127) / 128;

    // layer 1
    gemm_rt<<<GB, 256, 0, stream>>>(x, W1, dinv, bufA16, n);
    agg_csr128<<<(int)(((size_t)n * 64 + 255) / 256), 256, 0, stream>>>(
        rowptr, srcidx, dinv, bufA16, b1, bufB, n, 1);

    // layer 2
    gemm_rt<<<GB, 256, 0, stream>>>(bufB, Wh, dinv, bufA16, n);
    agg_csr128<<<(int)(((size_t)n * 64 + 255) / 256), 256, 0, stream>>>(
        rowptr, srcidx, dinv, bufA16, bh, bufB, n, 1);

    // layer 3 + output projection (fp32 path; ys reuses bufA16 region)
    dotw3<<<(int)(((size_t)n * 64 + 255) / 256), 256, 0, stream>>>(bufB, w3, dinv, ys, n);
    agg_csr_scalar<<<B, 256, 0, stream>>>(rowptr, srcidx, dinv, ys, c3, out, n);
}

// Round 8
// 325.282 us; speedup vs baseline: 2.2315x; 1.2686x over previous
//
#include <hip/hip_runtime.h>
#include <hip/hip_fp16.h>

// GCN: N=100000, E=1600000, F=H=128, D=64, O=1.
// R8: parallel segmented scan. scanA = one wave per bin (shuffle scan over
//     NB chunks, in-place excl prefix + binsum). scanK1/scanK3 deleted;
//     binbase folded into scatterH's offset load. Rest per R7 (fp16 gather).

#define F_DIM 128
#define CHUNK 8192

__global__ __launch_bounds__(256) void histH(const int* __restrict__ dst, int* __restrict__ hist,
                                             int E, int NBKT, int NB) {
    __shared__ int bins[1024];
    int blk = blockIdx.x;
    for (int i = threadIdx.x; i < NBKT; i += 256) bins[i] = 0;
    __syncthreads();
    int beg = blk * CHUNK, end = min(E, beg + CHUNK);
    for (int e = beg + threadIdx.x; e < end; e += 256)
        atomicAdd(&bins[dst[e] >> 7], 1);
    __syncthreads();
    for (int i = threadIdx.x; i < NBKT; i += 256)
        hist[i * NB + blk] = bins[i];
}

// ---- per-bin wave scan: hist[bin][0..NB) -> exclusive prefix (in place),
//      binsum[bin] = total. One 64-lane wave per bin. ----
__global__ __launch_bounds__(256) void scanA(int* __restrict__ hist, int* __restrict__ binsum,
                                             int NBKT, int NB) {
    int wave = (int)((blockIdx.x * (size_t)blockDim.x + threadIdx.x) >> 6);
    if (wave >= NBKT) return;
    int lane = threadIdx.x & 63;
    int* row = hist + (size_t)wave * NB;
    int running = 0;
    for (int b0 = 0; b0 < NB; b0 += 64) {
        int idx = b0 + lane;
        int v = (idx < NB) ? row[idx] : 0;
        int s = v;
#pragma unroll
        for (int off = 1; off < 64; off <<= 1) {
            int u = __shfl_up(s, off, 64);
            if (lane >= off) s += u;
        }
        if (idx < NB) row[idx] = running + s - v;   // exclusive
        running += __shfl(s, 63, 64);               // chunk total
    }
    if (lane == 0) binsum[wave] = running;
}

// ---- exclusive scan of bin totals -> bucket bases (NBKT <= 1024) ----
__global__ void scanK2(const int* __restrict__ binsum, int* __restrict__ binbase,
                       int NBKT, int E) {
    __shared__ int s[1024];
    int t = threadIdx.x;
    int v = (t < NBKT) ? binsum[t] : 0;
    s[t] = v;
    __syncthreads();
    for (int off = 1; off < 1024; off <<= 1) {
        int u = (t >= off) ? s[t - off] : 0;
        __syncthreads();
        s[t] += u;
        __syncthreads();
    }
    if (t < NBKT) binbase[t] = s[t] - v;
    if (t == 0) binbase[NBKT] = E;
}

// ---- bucketed scatter: tmp[] = (d&127)<<17 | src, grouped by bucket ----
// offs = binbase[bin] + local prefix (hist) : scanK3 folded in here.
__global__ __launch_bounds__(256) void scatterH(const int* __restrict__ src,
                                                const int* __restrict__ dst,
                                                const int* __restrict__ hist,
                                                const int* __restrict__ binbase,
                                                int* __restrict__ tmp,
                                                int E, int NBKT, int NB) {
    __shared__ int offs[1024];
    int blk = blockIdx.x;
    for (int i = threadIdx.x; i < NBKT; i += 256)
        offs[i] = hist[i * NB + blk] + binbase[i];
    __syncthreads();
    int beg = blk * CHUNK, end = min(E, beg + CHUNK);
    for (int e = beg + threadIdx.x; e < end; e += 256) {
        int d = dst[e];
        int pos = atomicAdd(&offs[d >> 7], 1);
        tmp[pos] = ((d & 127) << 17) | src[e];
    }
}

__global__ __launch_bounds__(256) void bucket_csr(const int* __restrict__ tmp,
                                                  const int* __restrict__ binbase,
                                                  int* __restrict__ rowptr,
                                                  int* __restrict__ srcidx,
                                                  float* __restrict__ dinv,
                                                  int n) {
    __shared__ int cnt[128], sc[128], cnt2[128];
    int b = blockIdx.x;
    int bstart = binbase[b], bend = binbase[b + 1];
    if (threadIdx.x < 128) cnt[threadIdx.x] = 0;
    __syncthreads();
    for (int e = bstart + threadIdx.x; e < bend; e += 256)
        atomicAdd(&cnt[tmp[e] >> 17], 1);
    __syncthreads();
    if (threadIdx.x < 128) sc[threadIdx.x] = cnt[threadIdx.x];
    __syncthreads();
    for (int off = 1; off < 128; off <<= 1) {
        int u = 0;
        if (threadIdx.x < 128 && threadIdx.x >= off) u = sc[threadIdx.x - off];
        __syncthreads();
        if (threadIdx.x < 128) sc[threadIdx.x] += u;
        __syncthreads();
    }
    if (threadIdx.x < 128) {
        int excl = sc[threadIdx.x] - cnt[threadIdx.x];
        cnt2[threadIdx.x] = excl;
        int id = b * 128 + threadIdx.x;
        if (id <= n) rowptr[id] = bstart + excl;
        if (id < n) dinv[id] = rsqrtf((float)cnt[threadIdx.x] + 1.0f);
    }
    __syncthreads();
    for (int e = bstart + threadIdx.x; e < bend; e += 256) {
        int p = tmp[e];
        int pos = bstart + atomicAdd(&cnt2[p >> 17], 1);
        srcidx[pos] = p & 0x1FFFF;
    }
}

__global__ void make_w3(const float* __restrict__ W2, const float* __restrict__ b2,
                        const float* __restrict__ Wo, const float* __restrict__ bo,
                        float* __restrict__ w3, float* __restrict__ c3) {
    int j = threadIdx.x;
    float s = 0.f;
    for (int d = 0; d < 64; ++d) s += W2[j * 64 + d] * Wo[d];
    w3[j] = s;
    if (j == 0) {
        float c = 0.f;
        for (int d = 0; d < 64; ++d) c += b2[d] * Wo[d];
        *c3 = c + bo[0];
    }
}

#define BK 32
#define LDP 132
__global__ __launch_bounds__(256, 4) void gemm_rt(const float* __restrict__ A,
                                                  const float* __restrict__ W,
                                                  const float* __restrict__ dinv,
                                                  __half* __restrict__ Ch, int n) {
    __shared__ float As[BK][LDP];
    __shared__ float Ws[BK][LDP];
    const int tid = threadIdx.x;
    const int tx = tid & 15;
    const int ty = tid >> 4;
    const int row0 = blockIdx.x * 128;

    float acc[8][8];
#pragma unroll
    for (int i = 0; i < 8; ++i)
#pragma unroll
        for (int j = 0; j < 8; ++j) acc[i][j] = 0.f;

    for (int kc = 0; kc < 128; kc += BK) {
#pragma unroll
        for (int i = 0; i < 4; ++i) {
            int idx = tid + 256 * i;
            int r = idx >> 3, q = idx & 7;
            int row = row0 + r;
            float4 v = (row < n) ? *(const float4*)(A + (size_t)row * 128 + kc + q * 4)
                                 : make_float4(0.f, 0.f, 0.f, 0.f);
            As[q * 4 + 0][r] = v.x;
            As[q * 4 + 1][r] = v.y;
            As[q * 4 + 2][r] = v.z;
            As[q * 4 + 3][r] = v.w;
        }
#pragma unroll
        for (int i = 0; i < 4; ++i) {
            int idx = tid + 256 * i;
            int k = idx >> 5, q = idx & 31;
            float4 v = *(const float4*)(W + (size_t)(kc + k) * 128 + q * 4);
            *(float4*)(&Ws[k][q * 4]) = v;
        }
        __syncthreads();

#pragma unroll 8
        for (int k = 0; k < BK; ++k) {
            float a[8], w[8];
            *(float4*)&a[0] = *(const float4*)(&As[k][ty * 4]);
            *(float4*)&a[4] = *(const float4*)(&As[k][64 + ty * 4]);
            *(float4*)&w[0] = *(const float4*)(&Ws[k][tx * 4]);
            *(float4*)&w[4] = *(const float4*)(&Ws[k][64 + tx * 4]);
#pragma unroll
            for (int i = 0; i < 8; ++i)
#pragma unroll
                for (int j = 0; j < 8; ++j)
                    acc[i][j] = fmaf(a[i], w[j], acc[i][j]);
        }
        __syncthreads();
    }

#pragma unroll
    for (int i = 0; i < 8; ++i) {
        int row = row0 + ty * 4 + (i & 3) + ((i >= 4) ? 64 : 0);
        if (row < n) {
            float di = dinv[row];
            __half2 p0 = __floats2half2_rn(acc[i][0] * di, acc[i][1] * di);
            __half2 p1 = __floats2half2_rn(acc[i][2] * di, acc[i][3] * di);
            __half2 p2 = __floats2half2_rn(acc[i][4] * di, acc[i][5] * di);
            __half2 p3 = __floats2half2_rn(acc[i][6] * di, acc[i][7] * di);
            uint2 w0, w1;
            w0.x = *(unsigned*)&p0; w0.y = *(unsigned*)&p1;
            w1.x = *(unsigned*)&p2; w1.y = *(unsigned*)&p3;
            *(uint2*)(Ch + (size_t)row * 128 + tx * 4) = w0;
            *(uint2*)(Ch + (size_t)row * 128 + 64 + tx * 4) = w1;
        }
    }
}

// out[d] = relu( dinv[d]*(sum_{s in in(d)} G[s] + G[d]) + b ), G fp16, accum fp32
__global__ __launch_bounds__(256) void agg_csr128(const int* __restrict__ rowptr,
                                                  const int* __restrict__ srcidx,
                                                  const float* __restrict__ dinv,
                                                  const __half* __restrict__ Gh,
                                                  const float* __restrict__ b,
                                                  float* __restrict__ out,
                                                  int n, int do_relu) {
    int wid = (int)((blockIdx.x * (size_t)blockDim.x + threadIdx.x) >> 6);
    if (wid >= n) return;
    int lane = threadIdx.x & 63;
    int q = lane >> 4;
    int l = lane & 15;
    int beg = rowptr[wid], end = rowptr[wid + 1];
    const int co = l * 8;

    float4 aLo = make_float4(0.f, 0.f, 0.f, 0.f);
    float4 aHi = make_float4(0.f, 0.f, 0.f, 0.f);

#define ACC16(u)                                                            \
    {                                                                       \
        float2 f0 = __half22float2(*(const __half2*)&(u).x);                \
        float2 f1 = __half22float2(*(const __half2*)&(u).y);                \
        float2 f2 = __half22float2(*(const __half2*)&(u).z);                \
        float2 f3 = __half22float2(*(const __half2*)&(u).w);                \
        aLo.x += f0.x; aLo.y += f0.y; aLo.z += f1.x; aLo.w += f1.y;         \
        aHi.x += f2.x; aHi.y += f2.y; aHi.z += f3.x; aHi.w += f3.y;         \
    }

    if (q == 0) {
        uint4 u = *(const uint4*)(Gh + (size_t)wid * 128 + co);
        ACC16(u);
    }

    int e = beg + q;
    for (; e + 4 < end; e += 8) {
        int s0 = srcidx[e], s1 = srcidx[e + 4];
        uint4 u0 = *(const uint4*)(Gh + (size_t)s0 * 128 + co);
        uint4 u1 = *(const uint4*)(Gh + (size_t)s1 * 128 + co);
        ACC16(u0);
        ACC16(u1);
    }
    for (; e < end; e += 4) {
        int s0 = srcidx[e];
        uint4 u0 = *(const uint4*)(Gh + (size_t)s0 * 128 + co);
        ACC16(u0);
    }
#undef ACC16

    aLo.x += __shfl_xor(aLo.x, 16, 64); aLo.y += __shfl_xor(aLo.y, 16, 64);
    aLo.z += __shfl_xor(aLo.z, 16, 64); aLo.w += __shfl_xor(aLo.w, 16, 64);
    aHi.x += __shfl_xor(aHi.x, 16, 64); aHi.y += __shfl_xor(aHi.y, 16, 64);
    aHi.z += __shfl_xor(aHi.z, 16, 64); aHi.w += __shfl_xor(aHi.w, 16, 64);
    aLo.x += __shfl_xor(aLo.x, 32, 64); aLo.y += __shfl_xor(aLo.y, 32, 64);
    aLo.z += __shfl_xor(aLo.z, 32, 64); aLo.w += __shfl_xor(aLo.w, 32, 64);
    aHi.x += __shfl_xor(aHi.x, 32, 64); aHi.y += __shfl_xor(aHi.y, 32, 64);
    aHi.z += __shfl_xor(aHi.z, 32, 64); aHi.w += __shfl_xor(aHi.w, 32, 64);

    if (lane < 16) {
        float di = dinv[wid];
        float4 b0 = *(const float4*)(b + co);
        float4 b1 = *(const float4*)(b + co + 4);
        float4 o0, o1;
        o0.x = di * aLo.x + b0.x; o0.y = di * aLo.y + b0.y;
        o0.z = di * aLo.z + b0.z; o0.w = di * aLo.w + b0.w;
        o1.x = di * aHi.x + b1.x; o1.y = di * aHi.y + b1.y;
        o1.z = di * aHi.z + b1.z; o1.w = di * aHi.w + b1.w;
        if (do_relu) {
            o0.x = fmaxf(o0.x, 0.f); o0.y = fmaxf(o0.y, 0.f);
            o0.z = fmaxf(o0.z, 0.f); o0.w = fmaxf(o0.w, 0.f);
            o1.x = fmaxf(o1.x, 0.f); o1.y = fmaxf(o1.y, 0.f);
            o1.z = fmaxf(o1.z, 0.f); o1.w = fmaxf(o1.w, 0.f);
        }
        float* orow = out + (size_t)wid * 128 + co;
        *(float4*)orow = o0;
        *(float4*)(orow + 4) = o1;
    }
}

__global__ __launch_bounds__(256) void dotw3(const float* __restrict__ H,
                                             const float* __restrict__ w3,
                                             const float* __restrict__ dinv,
                                             float* __restrict__ ys, int n) {
    int wid = (int)((blockIdx.x * (size_t)blockDim.x + threadIdx.x) >> 6);
    int lane = threadIdx.x & 63;
    if (wid >= n) return;
    float2 h = *(const float2*)(H + (size_t)wid * 128 + lane * 2);
    float2 w = *(const float2*)(w3 + lane * 2);
    float v = h.x * w.x + h.y * w.y;
#pragma unroll
    for (int off = 32; off > 0; off >>= 1) v += __shfl_down(v, off, 64);
    if (lane == 0) ys[wid] = v * dinv[wid];
}

__global__ void agg_csr_scalar(const int* __restrict__ rowptr, const int* __restrict__ srcidx,
                               const float* __restrict__ dinv, const float* __restrict__ ys,
                               const float* __restrict__ c3, float* __restrict__ out, int n) {
    int i = blockIdx.x * blockDim.x + threadIdx.x;
    if (i >= n) return;
    int beg = rowptr[i], end = rowptr[i + 1];
    float acc = ys[i];
    int e = beg;
    for (; e + 3 < end; e += 4) {
        acc += ys[srcidx[e]] + ys[srcidx[e + 1]] + ys[srcidx[e + 2]] + ys[srcidx[e + 3]];
    }
    for (; e < end; ++e) acc += ys[srcidx[e]];
    out[i] = dinv[i] * acc + c3[0];
}

static inline size_t align4(size_t x) { return (x + 3) & ~(size_t)3; }

extern "C" void kernel_launch(void* const* d_in, const int* in_sizes, int n_in,
                              void* d_out, int out_size, void* d_ws, size_t ws_size,
                              hipStream_t stream) {
    const float* x  = (const float*)d_in[0];
    const int* ei   = (const int*)d_in[1];
    const float* W1 = (const float*)d_in[2];
    const float* b1 = (const float*)d_in[3];
    const float* Wh = (const float*)d_in[4];
    const float* bh = (const float*)d_in[5];
    const float* W2 = (const float*)d_in[6];
    const float* b2 = (const float*)d_in[7];
    const float* Wo = (const float*)d_in[8];
    const float* bo = (const float*)d_in[9];
    float* out = (float*)d_out;

    const int n = in_sizes[0] / F_DIM;
    const int E = in_sizes[1] / 2;
    const int* src = ei;
    const int* dst = ei + E;

    const int NB = (E + CHUNK - 1) / CHUNK;
    const int NBKT = (n >> 7) + 1;

    size_t o = 0;
    int* rowptr = (int*)d_ws + o;        o = align4(o + n + 1);
    int* srcidx = (int*)d_ws + o;        o = align4(o + E);
    int* hist   = (int*)d_ws + o;        o = align4(o + (size_t)NBKT * NB);
    int* binsum = (int*)d_ws + o;        o = align4(o + NBKT);
    int* binbase= (int*)d_ws + o;        o = align4(o + NBKT + 1);
    float* dinv = (float*)d_ws + o;      o = align4(o + n);
    float* w3   = (float*)d_ws + o;      o = align4(o + 128);
    float* c3   = (float*)d_ws + o;      o = align4(o + 4);
    __half* bufA16 = (__half*)((int*)d_ws + o);  o = align4(o + (size_t)n * 64);  // n*128 halfs
    float* bufB = (float*)d_ws + o;      o = align4(o + (size_t)n * 128);
    int* tmp = (int*)bufA16;             // aliases bufA16 (consumed before gemm1)
    float* ys = (float*)bufA16;          // aliases bufA16 (free after agg2)

    const int B = (n + 255) / 256;

    // CSR build
    histH<<<NB, 256, 0, stream>>>(dst, hist, E, NBKT, NB);
    scanA<<<(NBKT * 64 + 255) / 256, 256, 0, stream>>>(hist, binsum, NBKT, NB);
    scanK2<<<1, 1024, 0, stream>>>(binsum, binbase, NBKT, E);
    scatterH<<<NB, 256, 0, stream>>>(src, dst, hist, binbase, tmp, E, NBKT, NB);
    bucket_csr<<<NBKT, 256, 0, stream>>>(tmp, binbase, rowptr, srcidx, dinv, n);
    make_w3<<<1, 128, 0, stream>>>(W2, b2, Wo, bo, w3, c3);

    const int GB = (n + 127) / 128;

    // layer 1
    gemm_rt<<<GB, 256, 0, stream>>>(x, W1, dinv, bufA16, n);
    agg_csr128<<<(int)(((size_t)n * 64 + 255) / 256), 256, 0, stream>>>(
        rowptr, srcidx, dinv, bufA16, b1, bufB, n, 1);

    // layer 2
    gemm_rt<<<GB, 256, 0, stream>>>(bufB, Wh, dinv, bufA16, n);
    agg_csr128<<<(int)(((size_t)n * 64 + 255) / 256), 256, 0, stream>>>(
        rowptr, srcidx, dinv, bufA16, bh, bufB, n, 1);

    // layer 3 + output projection (fp32 path; ys reuses bufA16 region)
    dotw3<<<(int)(((size_t)n * 64 + 255) / 256), 256, 0, stream>>>(bufB, w3, dinv, ys, n);
    agg_csr_scalar<<<B, 256, 0, stream>>>(rowptr, srcidx, dinv, ys, c3, out, n);
}

// Round 9
// 240.182 us; speedup vs baseline: 3.0222x; 1.3543x over previous
//
#include <hip/hip_runtime.h>
#include <hip/hip_fp16.h>

// GCN: N=100000, E=1600000, F=H=128, D=64, O=1.
// R9: MFMA fp16 GEMMs (16x16x32_f16, W^T fp16 in LDS), h1 stored fp16,
//     layer-3 dot fused into agg2 epilogue (h2 never materialized).
//     CSR build per R8 (bucket sort + wave scan).

#define CHUNK 8192
#define ASTR 136   // LDS stride in halves: 272B rows -> 16B-aligned 8-chunks

using f16x8 = __attribute__((ext_vector_type(8))) _Float16;
using f32x4 = __attribute__((ext_vector_type(4))) float;

// ================= CSR build (unchanged from R8) =================
__global__ __launch_bounds__(256) void histH(const int* __restrict__ dst, int* __restrict__ hist,
                                             int E, int NBKT, int NB) {
    __shared__ int bins[1024];
    int blk = blockIdx.x;
    for (int i = threadIdx.x; i < NBKT; i += 256) bins[i] = 0;
    __syncthreads();
    int beg = blk * CHUNK, end = min(E, beg + CHUNK);
    for (int e = beg + threadIdx.x; e < end; e += 256)
        atomicAdd(&bins[dst[e] >> 7], 1);
    __syncthreads();
    for (int i = threadIdx.x; i < NBKT; i += 256)
        hist[i * NB + blk] = bins[i];
}

__global__ __launch_bounds__(256) void scanA(int* __restrict__ hist, int* __restrict__ binsum,
                                             int NBKT, int NB) {
    int wave = (int)((blockIdx.x * (size_t)blockDim.x + threadIdx.x) >> 6);
    if (wave >= NBKT) return;
    int lane = threadIdx.x & 63;
    int* row = hist + (size_t)wave * NB;
    int running = 0;
    for (int b0 = 0; b0 < NB; b0 += 64) {
        int idx = b0 + lane;
        int v = (idx < NB) ? row[idx] : 0;
        int s = v;
#pragma unroll
        for (int off = 1; off < 64; off <<= 1) {
            int u = __shfl_up(s, off, 64);
            if (lane >= off) s += u;
        }
        if (idx < NB) row[idx] = running + s - v;
        running += __shfl(s, 63, 64);
    }
    if (lane == 0) binsum[wave] = running;
}

__global__ void scanK2(const int* __restrict__ binsum, int* __restrict__ binbase,
                       int NBKT, int E) {
    __shared__ int s[1024];
    int t = threadIdx.x;
    int v = (t < NBKT) ? binsum[t] : 0;
    s[t] = v;
    __syncthreads();
    for (int off = 1; off < 1024; off <<= 1) {
        int u = (t >= off) ? s[t - off] : 0;
        __syncthreads();
        s[t] += u;
        __syncthreads();
    }
    if (t < NBKT) binbase[t] = s[t] - v;
    if (t == 0) binbase[NBKT] = E;
}

__global__ __launch_bounds__(256) void scatterH(const int* __restrict__ src,
                                                const int* __restrict__ dst,
                                                const int* __restrict__ hist,
                                                const int* __restrict__ binbase,
                                                int* __restrict__ tmp,
                                                int E, int NBKT, int NB) {
    __shared__ int offs[1024];
    int blk = blockIdx.x;
    for (int i = threadIdx.x; i < NBKT; i += 256)
        offs[i] = hist[i * NB + blk] + binbase[i];
    __syncthreads();
    int beg = blk * CHUNK, end = min(E, beg + CHUNK);
    for (int e = beg + threadIdx.x; e < end; e += 256) {
        int d = dst[e];
        int pos = atomicAdd(&offs[d >> 7], 1);
        tmp[pos] = ((d & 127) << 17) | src[e];
    }
}

__global__ __launch_bounds__(256) void bucket_csr(const int* __restrict__ tmp,
                                                  const int* __restrict__ binbase,
                                                  int* __restrict__ rowptr,
                                                  int* __restrict__ srcidx,
                                                  float* __restrict__ dinv,
                                                  int n) {
    __shared__ int cnt[128], sc[128], cnt2[128];
    int b = blockIdx.x;
    int bstart = binbase[b], bend = binbase[b + 1];
    if (threadIdx.x < 128) cnt[threadIdx.x] = 0;
    __syncthreads();
    for (int e = bstart + threadIdx.x; e < bend; e += 256)
        atomicAdd(&cnt[tmp[e] >> 17], 1);
    __syncthreads();
    if (threadIdx.x < 128) sc[threadIdx.x] = cnt[threadIdx.x];
    __syncthreads();
    for (int off = 1; off < 128; off <<= 1) {
        int u = 0;
        if (threadIdx.x < 128 && threadIdx.x >= off) u = sc[threadIdx.x - off];
        __syncthreads();
        if (threadIdx.x < 128) sc[threadIdx.x] += u;
        __syncthreads();
    }
    if (threadIdx.x < 128) {
        int excl = sc[threadIdx.x] - cnt[threadIdx.x];
        cnt2[threadIdx.x] = excl;
        int id = b * 128 + threadIdx.x;
        if (id <= n) rowptr[id] = bstart + excl;
        if (id < n) dinv[id] = rsqrtf((float)cnt[threadIdx.x] + 1.0f);
    }
    __syncthreads();
    for (int e = bstart + threadIdx.x; e < bend; e += 256) {
        int p = tmp[e];
        int pos = bstart + atomicAdd(&cnt2[p >> 17], 1);
        srcidx[pos] = p & 0x1FFFF;
    }
}

// ====== prep: W^T fp16 tables (for MFMA B-operand) + w3 = W2@Wo, c3 ======
__global__ __launch_bounds__(256) void prep_w(const float* __restrict__ W1,
                                              const float* __restrict__ Wh,
                                              const float* __restrict__ W2,
                                              const float* __restrict__ b2,
                                              const float* __restrict__ Wo,
                                              const float* __restrict__ bo,
                                              __half* __restrict__ Wt1,
                                              __half* __restrict__ WtH,
                                              float* __restrict__ w3,
                                              float* __restrict__ c3) {
    const float* W = blockIdx.x ? Wh : W1;
    __half* Wt = blockIdx.x ? WtH : Wt1;
    // coalesced writes (Wt row-major in c), strided reads (L2 absorbs 64KB)
    for (int i = threadIdx.x; i < 16384; i += 256) {
        int c = i >> 7, k = i & 127;
        Wt[c * 128 + k] = __float2half(W[k * 128 + c]);
    }
    if (blockIdx.x == 0 && threadIdx.x < 128) {
        int j = threadIdx.x;
        float s = 0.f;
        for (int d = 0; d < 64; ++d) s += W2[j * 64 + d] * Wo[d];
        w3[j] = s;
        if (j == 0) {
            float c = 0.f;
            for (int d = 0; d < 64; ++d) c += b2[d] * Wo[d];
            *c3 = c + bo[0];
        }
    }
}

// ====== MFMA GEMM: Ch[n,128] = half(dinv[row] * (A[n,128] @ W)) ======
// A fp32 (layer1, converted on stage) or fp16 (layer2). Wt = W^T fp16.
// Block: 256 thr = 4 waves (2x2), tile 64 rows x 128 cols. K=128.
template<typename AT>
__global__ __launch_bounds__(256) void gemm_mfma(const AT* __restrict__ A,
                                                 const __half* __restrict__ Wt,
                                                 const float* __restrict__ dinv,
                                                 __half* __restrict__ Ch, int n) {
    __shared__ _Float16 Al[64 * ASTR];
    __shared__ _Float16 Wl[128 * ASTR];
    const int tid = threadIdx.x;
    const int row0 = blockIdx.x * 64;

    // stage W^T: 128 cols x 128 k, 8-half chunks
#pragma unroll
    for (int i = 0; i < 8; ++i) {
        int idx = tid + 256 * i;
        int c = idx >> 4, q = idx & 15;
        uint4 v = *(const uint4*)(Wt + c * 128 + q * 8);
        *(uint4*)(&Wl[c * ASTR + q * 8]) = v;
    }
    // stage A: 64 rows x 128 k (convert fp32->fp16 if needed)
#pragma unroll
    for (int i = 0; i < 4; ++i) {
        int idx = tid + 256 * i;
        int r = idx >> 4, q = idx & 15;
        int row = row0 + r;
        uint4 u;
        if constexpr (sizeof(AT) == 2) {
            u = (row < n) ? *(const uint4*)((const __half*)A + (size_t)row * 128 + q * 8)
                          : make_uint4(0u, 0u, 0u, 0u);
        } else {
            if (row < n) {
                const float* ap = (const float*)A + (size_t)row * 128 + q * 8;
                float4 v0 = *(const float4*)ap;
                float4 v1 = *(const float4*)(ap + 4);
                __half2 p0 = __floats2half2_rn(v0.x, v0.y);
                __half2 p1 = __floats2half2_rn(v0.z, v0.w);
                __half2 p2 = __floats2half2_rn(v1.x, v1.y);
                __half2 p3 = __floats2half2_rn(v1.z, v1.w);
                u.x = *(unsigned*)&p0; u.y = *(unsigned*)&p1;
                u.z = *(unsigned*)&p2; u.w = *(unsigned*)&p3;
            } else u = make_uint4(0u, 0u, 0u, 0u);
        }
        *(uint4*)(&Al[r * ASTR + q * 8]) = u;
    }
    __syncthreads();

    const int wave = tid >> 6, lane = tid & 63;
    const int wr = (wave >> 1) * 32;   // wave row offset within tile
    const int wc = (wave & 1) * 64;    // wave col offset
    const int l = lane & 15, g = lane >> 4;

    f32x4 acc[2][4];
#pragma unroll
    for (int i = 0; i < 2; ++i)
#pragma unroll
        for (int j = 0; j < 4; ++j) acc[i][j] = (f32x4){0.f, 0.f, 0.f, 0.f};

#pragma unroll
    for (int kk = 0; kk < 128; kk += 32) {
        int ko = kk + g * 8;
        // A frag: row = l (per 16-row tile), k = g*8..+8 ; B frag: col = l, same k
        f16x8 a0 = *(const f16x8*)(&Al[(wr + l) * ASTR + ko]);
        f16x8 a1 = *(const f16x8*)(&Al[(wr + 16 + l) * ASTR + ko]);
        f16x8 b0 = *(const f16x8*)(&Wl[(wc + l) * ASTR + ko]);
        f16x8 b1 = *(const f16x8*)(&Wl[(wc + 16 + l) * ASTR + ko]);
        f16x8 b2 = *(const f16x8*)(&Wl[(wc + 32 + l) * ASTR + ko]);
        f16x8 b3 = *(const f16x8*)(&Wl[(wc + 48 + l) * ASTR + ko]);
        acc[0][0] = __builtin_amdgcn_mfma_f32_16x16x32_f16(a0, b0, acc[0][0], 0, 0, 0);
        acc[0][1] = __builtin_amdgcn_mfma_f32_16x16x32_f16(a0, b1, acc[0][1], 0, 0, 0);
        acc[0][2] = __builtin_amdgcn_mfma_f32_16x16x32_f16(a0, b2, acc[0][2], 0, 0, 0);
        acc[0][3] = __builtin_amdgcn_mfma_f32_16x16x32_f16(a0, b3, acc[0][3], 0, 0, 0);
        acc[1][0] = __builtin_amdgcn_mfma_f32_16x16x32_f16(a1, b0, acc[1][0], 0, 0, 0);
        acc[1][1] = __builtin_amdgcn_mfma_f32_16x16x32_f16(a1, b1, acc[1][1], 0, 0, 0);
        acc[1][2] = __builtin_amdgcn_mfma_f32_16x16x32_f16(a1, b2, acc[1][2], 0, 0, 0);
        acc[1][3] = __builtin_amdgcn_mfma_f32_16x16x32_f16(a1, b3, acc[1][3], 0, 0, 0);
    }

    // D layout (m89-verified): col = lane&15, row = (lane>>4)*4 + reg
#pragma unroll
    for (int rt = 0; rt < 2; ++rt) {
#pragma unroll
        for (int j = 0; j < 4; ++j) {
            int row = row0 + wr + rt * 16 + g * 4 + j;
            if (row < n) {
                float di = dinv[row];
#pragma unroll
                for (int ct = 0; ct < 4; ++ct)
                    Ch[(size_t)row * 128 + wc + ct * 16 + l] =
                        __float2half(acc[rt][ct][j] * di);
            }
        }
    }
}

// ====== CSR gather (fp16 table, fp32 accum), quarter-wave streams ======
// MODE 0: Hout[d] = half( relu(dinv*(sum+self) + bias) )     (layer 1)
// MODE 1: ys[d]   = dinv * dot(relu(dinv*(sum+self)+bias), w3) (layer 2+3 fused)
template<int MODE>
__global__ __launch_bounds__(256) void agg_csr(const int* __restrict__ rowptr,
                                               const int* __restrict__ srcidx,
                                               const float* __restrict__ dinv,
                                               const __half* __restrict__ Gh,
                                               const float* __restrict__ bias,
                                               const float* __restrict__ w3,
                                               void* __restrict__ outp, int n) {
    int wid = (int)((blockIdx.x * (size_t)blockDim.x + threadIdx.x) >> 6);
    if (wid >= n) return;
    int lane = threadIdx.x & 63;
    int q = lane >> 4;
    int l = lane & 15;
    int beg = rowptr[wid], end = rowptr[wid + 1];
    const int co = l * 8;

    float4 aLo = make_float4(0.f, 0.f, 0.f, 0.f);
    float4 aHi = make_float4(0.f, 0.f, 0.f, 0.f);

#define ACC16(u)                                                            \
    {                                                                       \
        float2 f0 = __half22float2(*(const __half2*)&(u).x);                \
        float2 f1 = __half22float2(*(const __half2*)&(u).y);                \
        float2 f2 = __half22float2(*(const __half2*)&(u).z);                \
        float2 f3 = __half22float2(*(const __half2*)&(u).w);                \
        aLo.x += f0.x; aLo.y += f0.y; aLo.z += f1.x; aLo.w += f1.y;         \
        aHi.x += f2.x; aHi.y += f2.y; aHi.z += f3.x; aHi.w += f3.y;         \
    }

    if (q == 0) {  // self-loop
        uint4 u = *(const uint4*)(Gh + (size_t)wid * 128 + co);
        ACC16(u);
    }

    int e = beg + q;
    for (; e + 4 < end; e += 8) {
        int s0 = srcidx[e], s1 = srcidx[e + 4];
        uint4 u0 = *(const uint4*)(Gh + (size_t)s0 * 128 + co);
        uint4 u1 = *(const uint4*)(Gh + (size_t)s1 * 128 + co);
        ACC16(u0);
        ACC16(u1);
    }
    for (; e < end; e += 4) {
        int s0 = srcidx[e];
        uint4 u0 = *(const uint4*)(Gh + (size_t)s0 * 128 + co);
        ACC16(u0);
    }
#undef ACC16

    aLo.x += __shfl_xor(aLo.x, 16, 64); aLo.y += __shfl_xor(aLo.y, 16, 64);
    aLo.z += __shfl_xor(aLo.z, 16, 64); aLo.w += __shfl_xor(aLo.w, 16, 64);
    aHi.x += __shfl_xor(aHi.x, 16, 64); aHi.y += __shfl_xor(aHi.y, 16, 64);
    aHi.z += __shfl_xor(aHi.z, 16, 64); aHi.w += __shfl_xor(aHi.w, 16, 64);
    aLo.x += __shfl_xor(aLo.x, 32, 64); aLo.y += __shfl_xor(aLo.y, 32, 64);
    aLo.z += __shfl_xor(aLo.z, 32, 64); aLo.w += __shfl_xor(aLo.w, 32, 64);
    aHi.x += __shfl_xor(aHi.x, 32, 64); aHi.y += __shfl_xor(aHi.y, 32, 64);
    aHi.z += __shfl_xor(aHi.z, 32, 64); aHi.w += __shfl_xor(aHi.w, 32, 64);

    float di = dinv[wid];
    float4 b0 = *(const float4*)(bias + co);
    float4 b1 = *(const float4*)(bias + co + 4);
    float o0 = fmaxf(di * aLo.x + b0.x, 0.f);
    float o1 = fmaxf(di * aLo.y + b0.y, 0.f);
    float o2 = fmaxf(di * aLo.z + b0.z, 0.f);
    float o3 = fmaxf(di * aLo.w + b0.w, 0.f);
    float o4 = fmaxf(di * aHi.x + b1.x, 0.f);
    float o5 = fmaxf(di * aHi.y + b1.y, 0.f);
    float o6 = fmaxf(di * aHi.z + b1.z, 0.f);
    float o7 = fmaxf(di * aHi.w + b1.w, 0.f);

    if constexpr (MODE == 0) {
        if (lane < 16) {
            __half2 p0 = __floats2half2_rn(o0, o1);
            __half2 p1 = __floats2half2_rn(o2, o3);
            __half2 p2 = __floats2half2_rn(o4, o5);
            __half2 p3 = __floats2half2_rn(o6, o7);
            uint4 u;
            u.x = *(unsigned*)&p0; u.y = *(unsigned*)&p1;
            u.z = *(unsigned*)&p2; u.w = *(unsigned*)&p3;
            *(uint4*)((__half*)outp + (size_t)wid * 128 + co) = u;
        }
    } else {
        float4 w0 = *(const float4*)(w3 + co);
        float4 w1 = *(const float4*)(w3 + co + 4);
        float v = o0 * w0.x + o1 * w0.y + o2 * w0.z + o3 * w0.w
                + o4 * w1.x + o5 * w1.y + o6 * w1.z + o7 * w1.w;
        v += __shfl_xor(v, 1, 64);
        v += __shfl_xor(v, 2, 64);
        v += __shfl_xor(v, 4, 64);
        v += __shfl_xor(v, 8, 64);
        if (lane == 0) ((float*)outp)[wid] = di * v;
    }
}

// ---- scalar CSR gather for final output ----
__global__ void agg_csr_scalar(const int* __restrict__ rowptr, const int* __restrict__ srcidx,
                               const float* __restrict__ dinv, const float* __restrict__ ys,
                               const float* __restrict__ c3, float* __restrict__ out, int n) {
    int i = blockIdx.x * blockDim.x + threadIdx.x;
    if (i >= n) return;
    int beg = rowptr[i], end = rowptr[i + 1];
    float acc = ys[i];
    int e = beg;
    for (; e + 3 < end; e += 4) {
        acc += ys[srcidx[e]] + ys[srcidx[e + 1]] + ys[srcidx[e + 2]] + ys[srcidx[e + 3]];
    }
    for (; e < end; ++e) acc += ys[srcidx[e]];
    out[i] = dinv[i] * acc + c3[0];
}

static inline size_t align4(size_t x) { return (x + 3) & ~(size_t)3; }

extern "C" void kernel_launch(void* const* d_in, const int* in_sizes, int n_in,
                              void* d_out, int out_size, void* d_ws, size_t ws_size,
                              hipStream_t stream) {
    const float* x  = (const float*)d_in[0];
    const int* ei   = (const int*)d_in[1];
    const float* W1 = (const float*)d_in[2];
    const float* b1 = (const float*)d_in[3];
    const float* Wh = (const float*)d_in[4];
    const float* bh = (const float*)d_in[5];
    const float* W2 = (const float*)d_in[6];
    const float* b2 = (const float*)d_in[7];
    const float* Wo = (const float*)d_in[8];
    const float* bo = (const float*)d_in[9];
    float* out = (float*)d_out;

    const int n = in_sizes[0] / 128;
    const int E = in_sizes[1] / 2;
    const int* src = ei;
    const int* dst = ei + E;

    const int NB = (E + CHUNK - 1) / CHUNK;
    const int NBKT = (n >> 7) + 1;

    size_t o = 0;
    int* rowptr = (int*)d_ws + o;        o = align4(o + n + 1);
    int* srcidx = (int*)d_ws + o;        o = align4(o + E);
    int* hist   = (int*)d_ws + o;        o = align4(o + (size_t)NBKT * NB);
    int* binsum = (int*)d_ws + o;        o = align4(o + NBKT);
    int* binbase= (int*)d_ws + o;        o = align4(o + NBKT + 1);
    float* dinv = (float*)d_ws + o;      o = align4(o + n);
    float* w3   = (float*)d_ws + o;      o = align4(o + 128);
    float* c3   = (float*)d_ws + o;      o = align4(o + 4);
    __half* Wt1 = (__half*)((int*)d_ws + o);     o = align4(o + 8192);
    __half* WtH = (__half*)((int*)d_ws + o);     o = align4(o + 8192);
    __half* bufA16 = (__half*)((int*)d_ws + o);  o = align4(o + (size_t)n * 64);
    __half* bufB16 = (__half*)((int*)d_ws + o);  o = align4(o + (size_t)n * 64);
    int* tmp = (int*)bufA16;    // aliases bufA16 (consumed before gemm1 writes)
    float* ys = (float*)bufB16; // aliases bufB16 (h1 consumed by gemm2 by then)

    const int B = (n + 255) / 256;

    // CSR build
    histH<<<NB, 256, 0, stream>>>(dst, hist, E, NBKT, NB);
    scanA<<<(NBKT * 64 + 255) / 256, 256, 0, stream>>>(hist, binsum, NBKT, NB);
    scanK2<<<1, 1024, 0, stream>>>(binsum, binbase, NBKT, E);
    scatterH<<<NB, 256, 0, stream>>>(src, dst, hist, binbase, tmp, E, NBKT, NB);
    bucket_csr<<<NBKT, 256, 0, stream>>>(tmp, binbase, rowptr, srcidx, dinv, n);
    prep_w<<<2, 256, 0, stream>>>(W1, Wh, W2, b2, Wo, bo, Wt1, WtH, w3, c3);

    const int GG = (n + 63) / 64;
    const int GA = (int)(((size_t)n * 64 + 255) / 256);

    // layer 1: g1 = fp16(dinv*(x@W1)); h1 = fp16 agg
    gemm_mfma<float><<<GG, 256, 0, stream>>>(x, Wt1, dinv, bufA16, n);
    agg_csr<0><<<GA, 256, 0, stream>>>(rowptr, srcidx, dinv, bufA16, b1, w3, bufB16, n);

    // layer 2: g2 = fp16(dinv*(h1@Wh)); fused agg+relu+dot(w3) -> ys
    gemm_mfma<__half><<<GG, 256, 0, stream>>>(bufB16, WtH, dinv, bufA16, n);
    agg_csr<1><<<GA, 256, 0, stream>>>(rowptr, srcidx, dinv, bufA16, bh, w3, ys, n);

    // layer 3 scalar aggregation + constant
    agg_csr_scalar<<<B, 256, 0, stream>>>(rowptr, srcidx, dinv, ys, c3, out, n);
}